// Round 6
// baseline (1080.714 us; speedup 1.0000x reference)
//
#include <hip/hip_runtime.h>
#include <hip/hip_bf16.h>

#define HIDC 128
#define INPC 320
#define CC  448
#define HH  64
#define WWI 128
#define HW  8192   // 64*128

using bf16   = __hip_bfloat16;
using bf16x8 = __attribute__((ext_vector_type(8))) __bf16;
using bf16x4 = __attribute__((ext_vector_type(4))) __bf16;
using f32x4  = __attribute__((ext_vector_type(4))) float;

__device__ __forceinline__ float b2f(bf16 v) { return __bfloat162float(v); }
__device__ __forceinline__ bf16  f2b(float v) { return __float2bfloat16(v); }

// ---------------- per-tensor symmetric int8 fake-quant ----------------
// scale = max(max|w|,1e-8)/127 ; q = clip(rint(w/scale),-128,127)
// dw gates: store q*scale as f32. pw gates: store q as bf16 INTEGER (exact),
// scale applied in the GEMM epilogue -> no bf16 rounding on weights.
__global__ __launch_bounds__(256) void quant_kernel(
    const float* wdz, const float* wpz, const float* wdr, const float* wpr,
    const float* wdq, const float* wpq, float* qwd, bf16* qwp, float* scales)
{
  const float* src = nullptr; int n = 0; float* df = nullptr; bf16* db = nullptr;
  int sidx = -1;
  switch (blockIdx.x) {
    case 0: src = wdz; n = CC * 9;    df = qwd;                 break;
    case 1: src = wpz; n = HIDC * CC; db = qwp;                 sidx = 0; break;
    case 2: src = wdr; n = CC * 9;    df = qwd + 4096;          break;
    case 3: src = wpr; n = HIDC * CC; db = qwp + HIDC * CC;     sidx = 1; break;
    case 4: src = wdq; n = CC * 9;    df = qwd + 8192;          break;
    case 5: src = wpq; n = HIDC * CC; db = qwp + 2 * HIDC * CC; sidx = 2; break;
  }
  __shared__ float red[256];
  int tid = threadIdx.x;
  float m = 0.f;
  for (int i = tid; i < n; i += 256) m = fmaxf(m, fabsf(src[i]));
  red[tid] = m; __syncthreads();
  for (int s = 128; s > 0; s >>= 1) {
    if (tid < s) red[tid] = fmaxf(red[tid], red[tid + s]);
    __syncthreads();
  }
  float scale = fmaxf(red[0], 1e-8f) / 127.f;
  if (sidx >= 0 && tid == 0) scales[sidx] = scale;
  for (int i = tid; i < n; i += 256) {
    float q = rintf(src[i] / scale);             // RNE, matches jnp.round
    q = fminf(fmaxf(q, -128.f), 127.f);
    if (df) df[i] = q * scale;
    else    db[i] = f2b(q);                      // integer in [-128,127]: exact in bf16
  }
}

// ---------------- fused dwconv 3x3 + pointwise MFMA GEMM + epilogue ----------
// Block = 4-row x 32-col pixel tile (N=128). 7 chunks of 64 channels:
//   dwconv chunk -> LDS d-tile (B-frag layout, never global) -> MFMA accumulate.
// STAGE 0: gates z,r from (h,x). z -> zfrag (frag-native layout), rh=r*h -> NCHW
//          bf16 via LDS-staged 64B-clean stores.
// STAGE 1: gate q from (rh,x); out = (1-z)*h + z*tanh(q), direct f32 stores.
template <int STAGE>
__global__ __launch_bounds__(256, 2) void fused_kernel(
    const float* __restrict__ h, const float* __restrict__ x,
    const bf16*  __restrict__ rh_in,
    const float* __restrict__ wd0, const float* __restrict__ bd0,
    const float* __restrict__ wd1, const float* __restrict__ bd1,
    const bf16*  __restrict__ wp0, const bf16* __restrict__ wp1,
    const float* __restrict__ bp0, const float* __restrict__ bp1,
    const float* __restrict__ sc0p, const float* __restrict__ sc1p,
    const bf16*  __restrict__ zfrag_in,
    bf16*  __restrict__ zfrag_out, bf16* __restrict__ rh_out,
    float* __restrict__ out)
{
  // d-tile: [g][ks(2)][nt(8)][qs(4)][ln(16)][kj(8)] bf16 = 32 KB; reused for
  // rh epilogue staging [o(128)][n(128)].
  __shared__ __align__(16) bf16 lds[16384];

  const int tid = threadIdx.x;
  const int kgl = tid >> 5;          // 0..7  channel-octet within 64-chunk
  const int row = (tid >> 3) & 3;    // 0..3  tile row
  const int xq  = tid & 7;           // 0..7  4-px column group
  const int tc  = blockIdx.x & 3;    // col tile (32 px)
  const int tr  = blockIdx.x >> 2;   // row tile 0..15
  const int b   = blockIdx.y;
  const int y   = tr * 4 + row;
  const int xb  = tc * 32 + xq * 4;

  const int lane = tid & 63;
  const int wave = tid >> 6;
  const int quad = lane >> 4;
  const int lr   = lane & 15;
  const int m0   = wave * 32;

  f32x4 acc0[2][8] = {};
  f32x4 acc1[2][8] = {};             // dead for STAGE==1

  const int ksw = kgl >> 2, qsw = kgl & 3;
  const int ntb = row * 2 + (xq >> 2);
  const int lnb = (xq & 3) * 4;

  for (int c = 0; c < 7; c++) {
    const int cb  = c * 64;
    const int ch0 = cb + kgl * 8;
    const bool inh  = ch0 < HIDC;
    const bool useb = (STAGE == 1) && inh;
    const float* pf = inh ? ((STAGE == 0) ? h + ((size_t)b * HIDC + ch0) * HW : nullptr)
                          : x + ((size_t)b * INPC + (ch0 - HIDC)) * HW;
    const bf16*  pb = useb ? rh_in + ((size_t)b * HIDC + ch0) * HW : nullptr;

    bf16x8 pk0[4], pk1[4];
#pragma unroll
    for (int i = 0; i < 8; i++) {
      int ch = ch0 + i;
      float a0[4] = {0.f, 0.f, 0.f, 0.f};
      float a1[4] = {0.f, 0.f, 0.f, 0.f};
#pragma unroll
      for (int dy = -1; dy <= 1; dy++) {
        int yy = y + dy;
        bool vrow = (unsigned)yy < (unsigned)HH;
        float v[4]; float el = 0.f, er = 0.f;
        if (vrow) {
          if (useb) {
            bf16x4 t = *reinterpret_cast<const bf16x4*>(pb + (size_t)i * HW + yy * WWI + xb);
            v[0] = (float)t[0]; v[1] = (float)t[1]; v[2] = (float)t[2]; v[3] = (float)t[3];
          } else {
            f32x4 t = *reinterpret_cast<const f32x4*>(pf + (size_t)i * HW + yy * WWI + xb);
            v[0] = t[0]; v[1] = t[1]; v[2] = t[2]; v[3] = t[3];
          }
          if (xq == 0 && xb > 0)        // tile-boundary halo: REAL pixels
            el = useb ? b2f(pb[(size_t)i * HW + yy * WWI + xb - 1])
                      : pf[(size_t)i * HW + yy * WWI + xb - 1];
          if (xq == 7 && xb + 4 < WWI)
            er = useb ? b2f(pb[(size_t)i * HW + yy * WWI + xb + 4])
                      : pf[(size_t)i * HW + yy * WWI + xb + 4];
        } else { v[0] = v[1] = v[2] = v[3] = 0.f; }
        float vL = __shfl_up(v[3], 1);
        if (xq == 0) vL = el;
        float vR = __shfl_down(v[0], 1);
        if (xq == 7) vR = er;
        int t = ch * 9 + (dy + 1) * 3;
        float u0 = wd0[t], u1 = wd0[t + 1], u2 = wd0[t + 2];
        a0[0] += vL   * u0 + v[0] * u1 + v[1] * u2;
        a0[1] += v[0] * u0 + v[1] * u1 + v[2] * u2;
        a0[2] += v[1] * u0 + v[2] * u1 + v[3] * u2;
        a0[3] += v[2] * u0 + v[3] * u1 + vR   * u2;
        if (STAGE == 0) {
          float s0 = wd1[t], s1 = wd1[t + 1], s2 = wd1[t + 2];
          a1[0] += vL   * s0 + v[0] * s1 + v[1] * s2;
          a1[1] += v[0] * s0 + v[1] * s1 + v[2] * s2;
          a1[2] += v[1] * s0 + v[2] * s1 + v[3] * s2;
          a1[3] += v[2] * s0 + v[3] * s1 + vR   * s2;
        }
      }
      float bb0 = bd0[ch];
#pragma unroll
      for (int p = 0; p < 4; p++) pk0[p][i] = (__bf16)(a0[p] + bb0);
      if (STAGE == 0) {
        float bb1 = bd1[ch];
#pragma unroll
        for (int p = 0; p < 4; p++) pk1[p][i] = (__bf16)(a1[p] + bb1);
      }
    }
    __syncthreads();                 // prev chunk's GEMM done reading LDS
#pragma unroll
    for (int p = 0; p < 4; p++) {
      int base0 = ((((0 * 2 + ksw) * 8 + ntb) * 4 + qsw) * 16 + lnb + p) * 8;
      *reinterpret_cast<bf16x8*>(&lds[base0]) = pk0[p];
      if (STAGE == 0) {
        int base1 = ((((1 * 2 + ksw) * 8 + ntb) * 4 + qsw) * 16 + lnb + p) * 8;
        *reinterpret_cast<bf16x8*>(&lds[base1]) = pk1[p];
      }
    }
    __syncthreads();
#pragma unroll
    for (int ks = 0; ks < 2; ks++) {
      int k0 = cb + ks * 32;
      const bf16* w0r = wp0 + (size_t)(m0 + lr) * CC + k0 + quad * 8;
      bf16x8 a00 = *reinterpret_cast<const bf16x8*>(w0r);
      bf16x8 a01 = *reinterpret_cast<const bf16x8*>(w0r + 16 * CC);
      bf16x8 a10, a11;
      if (STAGE == 0) {
        const bf16* w1r = wp1 + (size_t)(m0 + lr) * CC + k0 + quad * 8;
        a10 = *reinterpret_cast<const bf16x8*>(w1r);
        a11 = *reinterpret_cast<const bf16x8*>(w1r + 16 * CC);
      }
#pragma unroll
      for (int nf = 0; nf < 8; nf++) {
        bf16x8 bf0 = *reinterpret_cast<const bf16x8*>(
            &lds[((((0 * 2 + ks) * 8 + nf) * 4 + quad) * 16 + lr) * 8]);
        acc0[0][nf] = __builtin_amdgcn_mfma_f32_16x16x32_bf16(a00, bf0, acc0[0][nf], 0, 0, 0);
        acc0[1][nf] = __builtin_amdgcn_mfma_f32_16x16x32_bf16(a01, bf0, acc0[1][nf], 0, 0, 0);
        if (STAGE == 0) {
          bf16x8 bf1 = *reinterpret_cast<const bf16x8*>(
              &lds[((((1 * 2 + ks) * 8 + nf) * 4 + quad) * 16 + lr) * 8]);
          acc1[0][nf] = __builtin_amdgcn_mfma_f32_16x16x32_bf16(a10, bf1, acc1[0][nf], 0, 0, 0);
          acc1[1][nf] = __builtin_amdgcn_mfma_f32_16x16x32_bf16(a11, bf1, acc1[1][nf], 0, 0, 0);
        }
      }
    }
  }

  // ---------------- epilogue (C/D: col(N)=lane&15, row(M)=quad*4+reg) --------
  float s0 = *sc0p;
  size_t zb = (size_t)(b * 64 + blockIdx.x) * 16384;   // zfrag block base

  if (STAGE == 0) {
    float s1 = *sc1p;
    // z -> frag-native layout [block][j(8)][tid(256)][8]: 4 KB contiguous/instr
#pragma unroll
    for (int mf = 0; mf < 2; mf++)
#pragma unroll
      for (int rr = 0; rr < 4; rr++) {
        int o = m0 + mf * 16 + quad * 4 + rr;
        float bz = bp0[o];
        bf16x8 zv;
#pragma unroll
        for (int nf = 0; nf < 8; nf++) {
          float pre = acc0[mf][nf][rr] * s0 + bz;
          zv[nf] = (__bf16)(1.f / (1.f + expf(-pre)));
        }
        *reinterpret_cast<bf16x8*>(zfrag_out + zb + (mf * 4 + rr) * 2048 + tid * 8) = zv;
      }
    // rh = sigmoid(r)*h -> LDS [o][n] -> 64B-aligned coalesced NCHW stores
    __syncthreads();
#pragma unroll
    for (int mf = 0; mf < 2; mf++)
#pragma unroll
      for (int rr = 0; rr < 4; rr++) {
        int o = m0 + mf * 16 + quad * 4 + rr;
        float br = bp1[o];
#pragma unroll
        for (int nf = 0; nf < 8; nf++) {
          float pre = acc1[mf][nf][rr] * s1 + br;
          float rv = 1.f / (1.f + expf(-pre));
          int n = nf * 16 + lr;
          int rt = n >> 5, ct = n & 31;
          size_t hidx = ((size_t)b * HIDC + o) * HW + (size_t)(tr * 4 + rt) * WWI + tc * 32 + ct;
          lds[o * 128 + n] = f2b(rv * h[hidx]);
        }
      }
    __syncthreads();
#pragma unroll
    for (int j = 0; j < 8; j++) {
      int seg = j * 64 + (tid >> 2);
      int sub = tid & 3;
      int o = seg >> 2, rt = seg & 3;
      size_t oidx = ((size_t)b * HIDC + o) * HW + (size_t)(tr * 4 + rt) * WWI + tc * 32 + sub * 8;
      *reinterpret_cast<bf16x8*>(rh_out + oidx) =
          *reinterpret_cast<bf16x8*>(&lds[o * 128 + rt * 32 + sub * 8]);
    }
  } else {
#pragma unroll
    for (int mf = 0; mf < 2; mf++)
#pragma unroll
      for (int rr = 0; rr < 4; rr++) {
        int o = m0 + mf * 16 + quad * 4 + rr;
        float bq = bp0[o];
        bf16x8 zv = *reinterpret_cast<const bf16x8*>(zfrag_in + zb + (mf * 4 + rr) * 2048 + tid * 8);
#pragma unroll
        for (int nf = 0; nf < 8; nf++) {
          float pre = acc0[mf][nf][rr] * s0 + bq;
          float qv = tanhf(pre);
          float z = (float)zv[nf];
          int n = nf * 16 + lr;
          int rt = n >> 5, ct = n & 31;
          size_t idx = ((size_t)b * HIDC + o) * HW + (size_t)(tr * 4 + rt) * WWI + tc * 32 + ct;
          out[idx] = (1.f - z) * h[idx] + z * qv;    // 16 lanes = 64 B line ✓
        }
      }
  }
}

extern "C" void kernel_launch(void* const* d_in, const int* in_sizes, int n_in,
                              void* d_out, int out_size, void* d_ws, size_t ws_size,
                              hipStream_t stream)
{
  const float* h   = (const float*)d_in[0];
  const float* x   = (const float*)d_in[1];
  const float* wdz = (const float*)d_in[2];
  const float* bdz = (const float*)d_in[3];
  const float* wpz = (const float*)d_in[4];
  const float* bpz = (const float*)d_in[5];
  const float* wdr = (const float*)d_in[6];
  const float* bdr = (const float*)d_in[7];
  const float* wpr = (const float*)d_in[8];
  const float* bpr = (const float*)d_in[9];
  const float* wdq = (const float*)d_in[10];
  const float* bdq = (const float*)d_in[11];
  const float* wpq = (const float*)d_in[12];
  const float* bpq = (const float*)d_in[13];

  char* ws = (char*)d_ws;
  float* qwd    = (float*)ws;                   // z @0 | r @4096 | q @8192 (f32)
  float* scales = qwd + 12288;                  // 3 floats
  bf16*  qwp    = (bf16*)(ws + 65536);          // 3 x 57344 bf16 (int8 values)
  bf16*  zfrag  = (bf16*)(ws + (1 << 20));      // 512 blk x 16384 = 16.8 MB
  bf16*  rh     = zfrag + (size_t)512 * 16384;  // 16.8 MB NCHW bf16

  quant_kernel<<<6, 256, 0, stream>>>(wdz, wpz, wdr, wpr, wdq, wpq, qwd, qwp, scales);

  dim3 fgrid(64, 8);   // (tile, batch): 512 blocks, 2/CU resident
  fused_kernel<0><<<fgrid, 256, 0, stream>>>(
      h, x, nullptr,
      qwd, bdz, qwd + 4096, bdr,
      qwp, qwp + HIDC * CC, bpz, bpr,
      scales + 0, scales + 1,
      nullptr, zfrag, rh, nullptr);

  fused_kernel<1><<<fgrid, 256, 0, stream>>>(
      h, x, rh,
      qwd + 8192, bdq, nullptr, nullptr,
      qwp + 2 * HIDC * CC, nullptr, bpq, nullptr,
      scales + 2, nullptr,
      zfrag, nullptr, nullptr, (float*)d_out);
}